// Round 7
// baseline (286.797 us; speedup 1.0000x reference)
//
#include <hip/hip_runtime.h>
#include <math.h>
#include <stdint.h>

// Chamfer loss, B=16, N=M=4096, D=3, fp32 in/out — MFMA formulation, R16.
//
// d^2(p,t) = |p|^2 + (|t|^2 - 2 p.t); the bracket via v_mfma_f32_32x32x16_f16:
//   A row (candidate): [tx, ty, tz, h1, h2, 0,0,0]   (k=0..7; hi-lane k=8..15 garbage)
//   B col (query):     [-2px,-2py,-2pz, 1, 1, 0,0,0] (k=0..7; k=8..15 ZERO -> annihilates A garbage)
// h1+h2 = two-f16 split of |t|^2 (fp32-accurate). Only error is f16 point
// quantization (~1e-3, passes).
//
// LEDGER: R9=76.0 base. R10=94.7 (per-block fence = L2 writeback, NEVER).
// R11=83.1 (same-address atomic burst, NEVER). R12=79.4 (confounded 3-way
// change). R13=76.5 NULL (load-depth). R14=76.5 NULL (footprint). R15=75.4
// (8x VMEM volume cut = only -0.6 => volume ~exonerated). Algebra: main ~20us
// vs ~4-5us issue floor; fence-corrected VALUBusy~39%, MfmaUtil~30% — waves
// stalled ~60%, no pipe saturated.
//
// R16 theory: the ONE clean untested lever is waves/SIMD. All prior variants
// ran 16 waves/CU (4/SIMD). R12's "64-VGPR clamp" excuse was WRONG — R11
// counters show the dual-chain main at VGPR_Count=52 < 64. R16 is the
// unconfounded TLP experiment: same 1024 blocks, same 128 queries/block, same
// dual-chain body, but 512-thread blocks: 8 waves split candidates 4 ways
// (cquar = wave>>1, 1024 cands = 16 tiles each; qset = wave&1).
// __launch_bounds__(512,8) -> 4 blocks/CU = 32 waves/CU (2x TLP), per-wave
// work halved, total work identical. Direct global loads (no LDS staging) to
// isolate the variable. Pre-commit: (a) VGPR=64+scratch => clamp artifact;
// (b) clean VGPR & still ~75 => TLP exonerated, declare roofline on R15.
//
// Fixed cost context: harness re-poisons ~256 MB ws each timed iter = ~41.5 us
// of fillBuffer at HBM roofline inside dur_us, + ~10 us graph/launch overhead.
// Untouchable floor ~55 us.

#define BATCH   16
#define NPTS    4096
#define THREADS 512                            // 8 waves/block
#define QPB     128                            // queries per block
#define NITEMS  (2 * BATCH * NPTS)             // 131072
#define MAIN_BLOCKS (2 * BATCH * (NPTS / QPB)) // 1024: 128 queries per block

typedef __attribute__((ext_vector_type(8)))  _Float16 half8;
typedef __attribute__((ext_vector_type(16))) float    floatx16;

union Pack16 { float4 f4; _Float16 h[8]; half8 h8; };

__global__ __launch_bounds__(256) void chamfer_prep(
    const float* __restrict__ pred, const float* __restrict__ target,
    float4* __restrict__ packP, float4* __restrict__ packT)
{
    int g = blockIdx.x * 256 + threadIdx.x;       // 0..131071
    int arr = g >> 16;                            // 0=pred, 1=target
    int pt  = g & 65535;                          // b*NPTS + n
    const float* src = arr ? target : pred;
    float x = src[pt * 3 + 0];
    float y = src[pt * 3 + 1];
    float z = src[pt * 3 + 2];
    _Float16 hx = (_Float16)x, hy = (_Float16)y, hz = (_Float16)z;
    float xf = (float)hx, yf = (float)hy, zf = (float)hz;
    float t = xf * xf + yf * yf + zf * zf;        // |q|^2 of the QUANTIZED point
    _Float16 h1 = (_Float16)t;
    _Float16 h2 = (_Float16)(t - (float)h1);
    Pack16 p;
    p.h[0] = hx; p.h[1] = hy; p.h[2] = hz; p.h[3] = h1; p.h[4] = h2;
    p.h[5] = (_Float16)0.0f; p.h[6] = (_Float16)0.0f; p.h[7] = (_Float16)0.0f;
    (arr ? packT : packP)[pt] = p.f4;
}

__device__ inline half8 make_bfrag(const Pack16& praw, bool lo) {
    half8 f;
#pragma unroll
    for (int i = 0; i < 8; ++i) f[i] = (_Float16)0.0f;
    if (lo) {
        f[0] = (_Float16)(praw.h[0] * (_Float16)-2.0f);  // exact x2 scale
        f[1] = (_Float16)(praw.h[1] * (_Float16)-2.0f);
        f[2] = (_Float16)(praw.h[2] * (_Float16)-2.0f);
        f[3] = (_Float16)1.0f;
        f[4] = (_Float16)1.0f;
    }
    return f;
}

__global__ __launch_bounds__(THREADS, 8) void chamfer_main(
    const float4* __restrict__ packP, const float4* __restrict__ packT,
    float* __restrict__ blocksum)
{
    __shared__ float pmin[8][64];   // per-wave mins for its 64 queries
    __shared__ float wsum[2];

    int tid  = threadIdx.x;
    int lane = tid & 63;
    int wave = tid >> 6;            // 0..7
    int qset  = wave & 1;           // query 64-set (0..1) within the block's 128
    int cquar = wave >> 1;          // candidate quarter (1024 candidates)
    int l31  = lane & 31;
    bool lo  = lane < 32;

    int id = blockIdx.x;
    int ng = id & 31; id >>= 5;     // query group (128 queries)
    int b  = id & 15; id >>= 4;
    int dir = id;                   // 0: queries=pred, candidates=target

    const float4* qpack = dir ? packT : packP;
    const float4* cpack = dir ? packP : packT;

    // Two B fragments per wave: queries [qbase, qbase+32) and [qbase+32, qbase+64).
    size_t qbase = (size_t)b * NPTS + ng * QPB + qset * 64;
    Pack16 prA, prB;
    prA.f4 = qpack[qbase + l31];
    prB.f4 = qpack[qbase + 32 + l31];
    half8 bfragA = make_bfrag(prA, lo);
    half8 bfragB = make_bfrag(prB, lo);

    const float4* cb = cpack + (size_t)b * NPTS + cquar * 1024;

    floatx16 zero, mnA, mnB;
#pragma unroll
    for (int r = 0; r < 16; ++r) { zero[r] = 0.0f; mnA[r] = 1e30f; mnB[r] = 1e30f; }

    // 16 tiles x 64 candidates (quarter of batch). Dual-chain body verbatim
    // (R9/R11, measured VGPR=52): two independent MFMA/min chains off shared
    // A-loads. With 8 waves/SIMD, TLP hides the per-wave stalls that 4
    // waves/SIMD could not.
#pragma unroll 2
    for (int t = 0; t < 16; ++t) {
        Pack16 a0, a1;
        a0.f4 = cb[t * 64 + l31];
        a1.f4 = cb[t * 64 + 32 + l31];
        floatx16 d0 = __builtin_amdgcn_mfma_f32_32x32x16_f16(a0.h8, bfragA, zero, 0, 0, 0);
        floatx16 d1 = __builtin_amdgcn_mfma_f32_32x32x16_f16(a0.h8, bfragB, zero, 0, 0, 0);
#pragma unroll
        for (int r = 0; r < 16; ++r) mnA[r] = fminf(d0[r], mnA[r]);
#pragma unroll
        for (int r = 0; r < 16; ++r) mnB[r] = fminf(d1[r], mnB[r]);
        floatx16 d2 = __builtin_amdgcn_mfma_f32_32x32x16_f16(a1.h8, bfragA, zero, 0, 0, 0);
        floatx16 d3 = __builtin_amdgcn_mfma_f32_32x32x16_f16(a1.h8, bfragB, zero, 0, 0, 0);
#pragma unroll
        for (int r = 0; r < 16; ++r) mnA[r] = fminf(d2[r], mnA[r]);
#pragma unroll
        for (int r = 0; r < 16; ++r) mnB[r] = fminf(d3[r], mnB[r]);
    }

    // Per-lane 16-reg min trees, fold row-halves across lane^32, publish both
    // query sets (cols l31 / l31+32 of pmin row).
    float mA = fminf(fminf(fminf(mnA[0], mnA[1]),   fminf(mnA[2], mnA[3])),
                     fminf(fminf(mnA[4], mnA[5]),   fminf(mnA[6], mnA[7])));
    mA = fminf(mA, fminf(fminf(fminf(mnA[8], mnA[9]),   fminf(mnA[10], mnA[11])),
                         fminf(fminf(mnA[12], mnA[13]), fminf(mnA[14], mnA[15]))));
    float mB = fminf(fminf(fminf(mnB[0], mnB[1]),   fminf(mnB[2], mnB[3])),
                     fminf(fminf(mnB[4], mnB[5]),   fminf(mnB[6], mnB[7])));
    mB = fminf(mB, fminf(fminf(fminf(mnB[8], mnB[9]),   fminf(mnB[10], mnB[11])),
                         fminf(fminf(mnB[12], mnB[13]), fminf(mnB[14], mnB[15]))));
    mA = fminf(mA, __shfl_xor(mA, 32));
    mB = fminf(mB, __shfl_xor(mB, 32));
    if (lo) {
        pmin[wave][l31]      = mA;
        pmin[wave][l31 + 32] = mB;
    }
    __syncthreads();

    // Waves 0-1: all 64 lanes finish one query each (query = ng*128 + wave*64
    // + lane): merge the FOUR candidate quarters (waves w, w+2, w+4, w+6),
    // add |p|^2, sqrt, full-wave sum.
    if (wave < 2) {
        float mm = fminf(fminf(pmin[wave][lane],     pmin[wave + 2][lane]),
                         fminf(pmin[wave + 4][lane], pmin[wave + 6][lane]));
        Pack16 pr;
        pr.f4 = qpack[(size_t)b * NPTS + ng * QPB + wave * 64 + lane];
        float psq = (float)pr.h[3] + (float)pr.h[4];
        float dist = sqrtf(fmaxf(mm + psq, 0.0f));
#pragma unroll
        for (int off = 1; off <= 32; off <<= 1)
            dist += __shfl_xor(dist, off);
        if (lane == 0) wsum[wave] = dist;
    }
    __syncthreads();

    if (tid == 0)
        blocksum[blockIdx.x] = wsum[0] + wsum[1];
}

__global__ __launch_bounds__(256) void chamfer_finish(
    const float4* __restrict__ bs, float* __restrict__ out)
{
    __shared__ float ws[4];
    int tid = threadIdx.x;
    float4 v = bs[tid];                   // 1024 block sums = 256 thr x float4
    float s = (v.x + v.y) + (v.z + v.w);
#pragma unroll
    for (int off = 1; off <= 32; off <<= 1)
        s += __shfl_xor(s, off);
    int lane = tid & 63, wave = tid >> 6;
    if (lane == 0) ws[wave] = s;
    __syncthreads();
    if (tid == 0) out[0] = (ws[0] + ws[1] + ws[2] + ws[3]) * (1.0f / (float)NITEMS);
}

extern "C" void kernel_launch(void* const* d_in, const int* in_sizes, int n_in,
                              void* d_out, int out_size, void* d_ws, size_t ws_size,
                              hipStream_t stream) {
    const float* pred   = (const float*)d_in[0];
    const float* target = (const float*)d_in[1];
    float* out = (float*)d_out;

    float4* packP = (float4*)d_ws;                              // 1 MB
    float4* packT = packP + (size_t)BATCH * NPTS;               // 1 MB
    float*  blocksum = (float*)(packT + (size_t)BATCH * NPTS);  // 4 KB

    chamfer_prep<<<NITEMS / 256, 256, 0, stream>>>(pred, target, packP, packT);
    chamfer_main<<<MAIN_BLOCKS, THREADS, 0, stream>>>(packP, packT, blocksum);
    chamfer_finish<<<1, 256, 0, stream>>>((const float4*)blocksum, out);
}

// Round 8
// 78.002 us; speedup vs baseline: 3.6768x; 3.6768x over previous
//
#include <hip/hip_runtime.h>
#include <math.h>
#include <stdint.h>

// Chamfer loss, B=16, N=M=4096, D=3, fp32 in/out — MFMA formulation, R17.
//
// d^2(p,t) = |p|^2 + (|t|^2 - 2 p.t); the bracket via v_mfma_f32_32x32x16_f16:
//   A row (candidate): [tx, ty, tz, h1, h2, 0,0,0]   (k=0..7; hi-lane k=8..15 garbage)
//   B col (query):     [-2px,-2py,-2pz, 1, 1, 0,0,0] (k=0..7; k=8..15 ZERO -> annihilates A garbage)
// h1+h2 = two-f16 split of |t|^2 (fp32-accurate). Only error is f16 point
// quantization (~1e-3, passes).
//
// LEDGER: R9=76.0 base. R10=94.7 (per-block fence = L2 writeback, NEVER).
// R11=83.1 (same-address atomic burst, NEVER). R12=79.4 (confounded).
// R13=76.5 NULL (load-depth). R14=76.5 NULL (footprint). R15=75.4 BEST
// (8x VMEM volume cut = only -0.6). R16=286.8 INVALID (lb(512,8) 64-VGPR
// clamp -> accumulators spilled to scratch: VGPR=32, 1.16 GB/iter scratch
// traffic. The allocator hammer, not a TLP test).
//
// R17 insight from the R16 wreck: dual-chain VGPR=52 < 64 means the HW
// already permits 8 waves/SIMD (occupancy steps at vgpr 64) — R9's 16
// waves/CU was limited by GRID (1024 blk x 256 thr = 4 blk/CU), not regs.
// R17 = clean TLP x2: 2048 blocks x 64 queries, lb(256,4) (cap 128, no
// allocator pressure), dual-chain body verbatim; wave = candidate quarter
// (1024 cands, 16 tiles), all 4 waves share the block's 64 queries.
// 8 blk/CU = 32 waves/CU from grid pressure alone. Pre-commit: VGPR must
// come back 52 with FETCH ~8 MB (no scratch); null (~75-76) => TLP is the
// last exonerated lever, declare roofline on R15.
//
// Fixed cost context: harness re-poisons ~256 MB ws each timed iter = ~41.5 us
// of fillBuffer at HBM roofline inside dur_us, + ~10 us graph/launch overhead.
// Untouchable floor ~55 us.

#define BATCH   16
#define NPTS    4096
#define THREADS 256                            // 4 waves/block
#define QPB     64                             // queries per block
#define NITEMS  (2 * BATCH * NPTS)             // 131072
#define MAIN_BLOCKS (2 * BATCH * (NPTS / QPB)) // 2048: 64 queries per block

typedef __attribute__((ext_vector_type(8)))  _Float16 half8;
typedef __attribute__((ext_vector_type(16))) float    floatx16;

union Pack16 { float4 f4; _Float16 h[8]; half8 h8; };

__global__ __launch_bounds__(256) void chamfer_prep(
    const float* __restrict__ pred, const float* __restrict__ target,
    float4* __restrict__ packP, float4* __restrict__ packT)
{
    int g = blockIdx.x * 256 + threadIdx.x;       // 0..131071
    int arr = g >> 16;                            // 0=pred, 1=target
    int pt  = g & 65535;                          // b*NPTS + n
    const float* src = arr ? target : pred;
    float x = src[pt * 3 + 0];
    float y = src[pt * 3 + 1];
    float z = src[pt * 3 + 2];
    _Float16 hx = (_Float16)x, hy = (_Float16)y, hz = (_Float16)z;
    float xf = (float)hx, yf = (float)hy, zf = (float)hz;
    float t = xf * xf + yf * yf + zf * zf;        // |q|^2 of the QUANTIZED point
    _Float16 h1 = (_Float16)t;
    _Float16 h2 = (_Float16)(t - (float)h1);
    Pack16 p;
    p.h[0] = hx; p.h[1] = hy; p.h[2] = hz; p.h[3] = h1; p.h[4] = h2;
    p.h[5] = (_Float16)0.0f; p.h[6] = (_Float16)0.0f; p.h[7] = (_Float16)0.0f;
    (arr ? packT : packP)[pt] = p.f4;
}

__device__ inline half8 make_bfrag(const Pack16& praw, bool lo) {
    half8 f;
#pragma unroll
    for (int i = 0; i < 8; ++i) f[i] = (_Float16)0.0f;
    if (lo) {
        f[0] = (_Float16)(praw.h[0] * (_Float16)-2.0f);  // exact x2 scale
        f[1] = (_Float16)(praw.h[1] * (_Float16)-2.0f);
        f[2] = (_Float16)(praw.h[2] * (_Float16)-2.0f);
        f[3] = (_Float16)1.0f;
        f[4] = (_Float16)1.0f;
    }
    return f;
}

__global__ __launch_bounds__(THREADS, 4) void chamfer_main(
    const float4* __restrict__ packP, const float4* __restrict__ packT,
    float* __restrict__ blocksum)
{
    __shared__ float pmin[4][64];   // per-wave mins for the block's 64 queries
    __shared__ float wsum[1];

    int tid  = threadIdx.x;
    int lane = tid & 63;
    int wave = tid >> 6;            // 0..3 = candidate quarter
    int l31  = lane & 31;
    bool lo  = lane < 32;

    int id = blockIdx.x;
    int ng = id & 63; id >>= 6;     // query group (64 queries)
    int b  = id & 15; id >>= 4;
    int dir = id;                   // 0: queries=pred, candidates=target

    const float4* qpack = dir ? packT : packP;
    const float4* cpack = dir ? packP : packT;

    // Two B fragments per wave (shared across waves): queries [qbase, qbase+64).
    size_t qbase = (size_t)b * NPTS + ng * QPB;
    Pack16 prA, prB;
    prA.f4 = qpack[qbase + l31];
    prB.f4 = qpack[qbase + 32 + l31];
    half8 bfragA = make_bfrag(prA, lo);
    half8 bfragB = make_bfrag(prB, lo);

    const float4* cb = cpack + (size_t)b * NPTS + (size_t)wave * 1024;

    floatx16 zero, mnA, mnB;
#pragma unroll
    for (int r = 0; r < 16; ++r) { zero[r] = 0.0f; mnA[r] = 1e30f; mnB[r] = 1e30f; }

    // 16 tiles x 64 candidates (this wave's quarter). Dual-chain body
    // verbatim (R9/R11, VGPR=52): two independent MFMA/min chains off shared
    // A-loads. 8 blocks/CU -> 32 waves/CU: TLP now hides per-wave stalls.
#pragma unroll 2
    for (int t = 0; t < 16; ++t) {
        Pack16 a0, a1;
        a0.f4 = cb[t * 64 + l31];
        a1.f4 = cb[t * 64 + 32 + l31];
        floatx16 d0 = __builtin_amdgcn_mfma_f32_32x32x16_f16(a0.h8, bfragA, zero, 0, 0, 0);
        floatx16 d1 = __builtin_amdgcn_mfma_f32_32x32x16_f16(a0.h8, bfragB, zero, 0, 0, 0);
#pragma unroll
        for (int r = 0; r < 16; ++r) mnA[r] = fminf(d0[r], mnA[r]);
#pragma unroll
        for (int r = 0; r < 16; ++r) mnB[r] = fminf(d1[r], mnB[r]);
        floatx16 d2 = __builtin_amdgcn_mfma_f32_32x32x16_f16(a1.h8, bfragA, zero, 0, 0, 0);
        floatx16 d3 = __builtin_amdgcn_mfma_f32_32x32x16_f16(a1.h8, bfragB, zero, 0, 0, 0);
#pragma unroll
        for (int r = 0; r < 16; ++r) mnA[r] = fminf(d2[r], mnA[r]);
#pragma unroll
        for (int r = 0; r < 16; ++r) mnB[r] = fminf(d3[r], mnB[r]);
    }

    // Per-lane 16-reg min trees, fold row-halves across lane^32, publish both
    // query 32-sets (cols l31 / l31+32 of pmin row).
    float mA = fminf(fminf(fminf(mnA[0], mnA[1]),   fminf(mnA[2], mnA[3])),
                     fminf(fminf(mnA[4], mnA[5]),   fminf(mnA[6], mnA[7])));
    mA = fminf(mA, fminf(fminf(fminf(mnA[8], mnA[9]),   fminf(mnA[10], mnA[11])),
                         fminf(fminf(mnA[12], mnA[13]), fminf(mnA[14], mnA[15]))));
    float mB = fminf(fminf(fminf(mnB[0], mnB[1]),   fminf(mnB[2], mnB[3])),
                     fminf(fminf(mnB[4], mnB[5]),   fminf(mnB[6], mnB[7])));
    mB = fminf(mB, fminf(fminf(fminf(mnB[8], mnB[9]),   fminf(mnB[10], mnB[11])),
                         fminf(fminf(mnB[12], mnB[13]), fminf(mnB[14], mnB[15]))));
    mA = fminf(mA, __shfl_xor(mA, 32));
    mB = fminf(mB, __shfl_xor(mB, 32));
    if (lo) {
        pmin[wave][l31]      = mA;
        pmin[wave][l31 + 32] = mB;
    }
    __syncthreads();

    // Wave 0: 64 lanes finish one query each (query = ng*64 + lane): merge
    // the four candidate quarters, add |p|^2, sqrt, full-wave sum.
    if (wave == 0) {
        float mm = fminf(fminf(pmin[0][lane], pmin[1][lane]),
                         fminf(pmin[2][lane], pmin[3][lane]));
        Pack16 pr;
        pr.f4 = qpack[qbase + lane];
        float psq = (float)pr.h[3] + (float)pr.h[4];
        float dist = sqrtf(fmaxf(mm + psq, 0.0f));
#pragma unroll
        for (int off = 1; off <= 32; off <<= 1)
            dist += __shfl_xor(dist, off);
        if (lane == 0) blocksum[blockIdx.x] = dist;
    }
}

__global__ __launch_bounds__(256) void chamfer_finish(
    const float4* __restrict__ bs, float* __restrict__ out)
{
    __shared__ float ws[4];
    int tid = threadIdx.x;
    float4 v0 = bs[tid];                  // 2048 block sums = 256 thr x 2 float4
    float4 v1 = bs[tid + 256];
    float s = ((v0.x + v0.y) + (v0.z + v0.w)) + ((v1.x + v1.y) + (v1.z + v1.w));
#pragma unroll
    for (int off = 1; off <= 32; off <<= 1)
        s += __shfl_xor(s, off);
    int lane = tid & 63, wave = tid >> 6;
    if (lane == 0) ws[wave] = s;
    __syncthreads();
    if (tid == 0) out[0] = (ws[0] + ws[1] + ws[2] + ws[3]) * (1.0f / (float)NITEMS);
}

extern "C" void kernel_launch(void* const* d_in, const int* in_sizes, int n_in,
                              void* d_out, int out_size, void* d_ws, size_t ws_size,
                              hipStream_t stream) {
    const float* pred   = (const float*)d_in[0];
    const float* target = (const float*)d_in[1];
    float* out = (float*)d_out;

    float4* packP = (float4*)d_ws;                              // 1 MB
    float4* packT = packP + (size_t)BATCH * NPTS;               // 1 MB
    float*  blocksum = (float*)(packT + (size_t)BATCH * NPTS);  // 8 KB

    chamfer_prep<<<NITEMS / 256, 256, 0, stream>>>(pred, target, packP, packT);
    chamfer_main<<<MAIN_BLOCKS, THREADS, 0, stream>>>(packP, packT, blocksum);
    chamfer_finish<<<1, 256, 0, stream>>>((const float4*)blocksum, out);
}

// Round 9
// 75.364 us; speedup vs baseline: 3.8055x; 1.0350x over previous
//
#include <hip/hip_runtime.h>
#include <math.h>
#include <stdint.h>

// Chamfer loss, B=16, N=M=4096, D=3, fp32 in/out — MFMA formulation, R18
// (= R15 verbatim, the session's best at 75.4us; restored after the R16/R17
// TLP arc closed the lever matrix).
//
// d^2(p,t) = |p|^2 + (|t|^2 - 2 p.t); the bracket via v_mfma_f32_32x32x16_f16:
//   A row (candidate): [tx, ty, tz, h1, h2, 0,0,0]   (k=0..7; hi-lane k=8..15 garbage)
//   B col (query):     [-2px,-2py,-2pz, 1, 1, 0,0,0] (k=0..7; k=8..15 ZERO -> annihilates A garbage)
// h1+h2 = two-f16 split of |t|^2 (fp32-accurate). Only error is f16 point
// quantization (~1e-3, passes).
//
// FINAL LEDGER:
//   R9 =76.0  baseline (1024 blk, dual-chain, VGPR=52)
//   R10=94.7  per-block __threadfence = buffer_wbl2 L2 writeback. NEVER.
//   R11=83.1  1024 same-address atomicAdd = serialized burst tail. NEVER.
//   R12=79.4  confounded (clamp + geometry)
//   R13=76.5  NULL — per-wave LDS ring, global_load_lds, counted vmcnt
//   R14=76.5  NULL — per-CU footprint halved
//   R15=75.4  BEST — 8x VMEM volume cut via block-shared LDS staging (-0.6)
//   R16=286.8 INVALID — lb(512,8) 64-VGPR clamp spilled accumulators
//   R17=78.0  NULL — clean 32 waves/CU test; +2.6 = doubled per-block cost
// Lever matrix complete: ILP, load-depth, footprint, volume, TLP all measured;
// none move main meaningfully. main ~20us is issue-structure-pinned; dur_us
// is dominated by the 41.5us ws re-poison + ~10us graph overhead (untouchable)
// + prep ~3 + finish ~1.5. ROOFLINE.

#define BATCH   16
#define NPTS    4096
#define THREADS 512                            // 8 waves/block
#define QPB     256                            // queries per block
#define NITEMS  (2 * BATCH * NPTS)             // 131072
#define MAIN_BLOCKS (2 * BATCH * (NPTS / QPB)) // 512: 256 queries per block

typedef __attribute__((ext_vector_type(8)))  _Float16 half8;
typedef __attribute__((ext_vector_type(16))) float    floatx16;

union Pack16 { float4 f4; _Float16 h[8]; half8 h8; };

// global->LDS DMA: wave-uniform LDS base, per-lane global addr, 16 B/lane.
#define GLL(gsrc, ldst)                                                        \
    __builtin_amdgcn_global_load_lds(                                          \
        (const __attribute__((address_space(1))) void*)(gsrc),                 \
        (__attribute__((address_space(3))) void*)(ldst), 16, 0, 0)

__global__ __launch_bounds__(256) void chamfer_prep(
    const float* __restrict__ pred, const float* __restrict__ target,
    float4* __restrict__ packP, float4* __restrict__ packT)
{
    int g = blockIdx.x * 256 + threadIdx.x;       // 0..131071
    int arr = g >> 16;                            // 0=pred, 1=target
    int pt  = g & 65535;                          // b*NPTS + n
    const float* src = arr ? target : pred;
    float x = src[pt * 3 + 0];
    float y = src[pt * 3 + 1];
    float z = src[pt * 3 + 2];
    _Float16 hx = (_Float16)x, hy = (_Float16)y, hz = (_Float16)z;
    float xf = (float)hx, yf = (float)hy, zf = (float)hz;
    float t = xf * xf + yf * yf + zf * zf;        // |q|^2 of the QUANTIZED point
    _Float16 h1 = (_Float16)t;
    _Float16 h2 = (_Float16)(t - (float)h1);
    Pack16 p;
    p.h[0] = hx; p.h[1] = hy; p.h[2] = hz; p.h[3] = h1; p.h[4] = h2;
    p.h[5] = (_Float16)0.0f; p.h[6] = (_Float16)0.0f; p.h[7] = (_Float16)0.0f;
    (arr ? packT : packP)[pt] = p.f4;
}

__device__ inline half8 make_bfrag(const Pack16& praw, bool lo) {
    half8 f;
#pragma unroll
    for (int i = 0; i < 8; ++i) f[i] = (_Float16)0.0f;
    if (lo) {
        f[0] = (_Float16)(praw.h[0] * (_Float16)-2.0f);  // exact x2 scale
        f[1] = (_Float16)(praw.h[1] * (_Float16)-2.0f);
        f[2] = (_Float16)(praw.h[2] * (_Float16)-2.0f);
        f[3] = (_Float16)1.0f;
        f[4] = (_Float16)1.0f;
    }
    return f;
}

__global__ __launch_bounds__(THREADS, 2) void chamfer_main(
    const float4* __restrict__ packP, const float4* __restrict__ packT,
    float* __restrict__ blocksum)
{
    __shared__ Pack16 bufA[1024];   // chalf0 chunk (16 KB), waves 0-3
    __shared__ Pack16 bufB[1024];   // chalf1 chunk (16 KB), waves 4-7
    __shared__ float pmin[8][64];   // per-wave mins for its 64 queries
    __shared__ float wsum[4];

    int tid  = threadIdx.x;
    int lane = tid & 63;
    int wave = tid >> 6;            // 0..7
    int qhalf = wave & 3;           // query 64-set (0..3) within the block's 256
    int chalf = wave >> 2;          // candidate half (2048 candidates)
    int l31  = lane & 31;
    bool lo  = lane < 32;

    int id = blockIdx.x;
    int ng = id & 15; id >>= 4;     // query group (256 queries)
    int b  = id & 15; id >>= 4;
    int dir = id;                   // 0: queries=pred, candidates=target

    const float4* qpack = dir ? packT : packP;
    const float4* cpack = dir ? packP : packT;

    // Two B fragments per wave: queries [qbase, qbase+32) and [qbase+32, qbase+64).
    size_t qbase = (size_t)b * NPTS + ng * QPB + qhalf * 64;
    Pack16 prA, prB;
    prA.f4 = qpack[qbase + l31];
    prB.f4 = qpack[qbase + 32 + l31];
    half8 bfragA = make_bfrag(prA, lo);
    half8 bfragB = make_bfrag(prB, lo);

    const float4* cb = cpack + (size_t)b * NPTS;   // all 4096 candidates of batch b

    floatx16 zero, mnA, mnB;
#pragma unroll
    for (int r = 0; r < 16; ++r) { zero[r] = 0.0f; mnA[r] = 1e30f; mnB[r] = 1e30f; }

    // 2 phases x 1024 candidates per chalf. Staging: waves 0-3 fill bufA
    // (chalf0 chunk), waves 4-7 fill bufB (chalf1 chunk) — each tile is loaded
    // from L2 ONCE per block and consumed by 4 waves. Compute body reads LDS.
#pragma unroll 1
    for (int k = 0; k < 2; ++k) {
        if (k) __syncthreads();     // all waves done reading bufs of phase k-1
        if (wave < 4) {
            const float4* srcA = cb + k * 1024;            // chalf0 chunk
#pragma unroll
            for (int i = 0; i < 4; ++i)
                GLL(srcA + wave * 256 + i * 64 + lane, &bufA[wave * 256 + i * 64]);
        } else {
            const float4* srcB = cb + 2048 + k * 1024;     // chalf1 chunk
#pragma unroll
            for (int i = 0; i < 4; ++i)
                GLL(srcB + (wave - 4) * 256 + i * 64 + lane, &bufB[(wave - 4) * 256 + i * 64]);
        }
        __syncthreads();            // gll queue drains (vmcnt) before barrier

        const Pack16* buf = (wave < 4) ? bufA : bufB;
#pragma unroll 2
        for (int t = 0; t < 16; ++t) {
            Pack16 a0, a1;
            a0.f4 = buf[t * 64 + l31].f4;
            a1.f4 = buf[t * 64 + 32 + l31].f4;
            floatx16 d0 = __builtin_amdgcn_mfma_f32_32x32x16_f16(a0.h8, bfragA, zero, 0, 0, 0);
            floatx16 d1 = __builtin_amdgcn_mfma_f32_32x32x16_f16(a0.h8, bfragB, zero, 0, 0, 0);
#pragma unroll
            for (int r = 0; r < 16; ++r) mnA[r] = fminf(d0[r], mnA[r]);
#pragma unroll
            for (int r = 0; r < 16; ++r) mnB[r] = fminf(d1[r], mnB[r]);
            floatx16 d2 = __builtin_amdgcn_mfma_f32_32x32x16_f16(a1.h8, bfragA, zero, 0, 0, 0);
            floatx16 d3 = __builtin_amdgcn_mfma_f32_32x32x16_f16(a1.h8, bfragB, zero, 0, 0, 0);
#pragma unroll
            for (int r = 0; r < 16; ++r) mnA[r] = fminf(d2[r], mnA[r]);
#pragma unroll
            for (int r = 0; r < 16; ++r) mnB[r] = fminf(d3[r], mnB[r]);
        }
    }

    // Per-lane 16-reg min trees, fold row-halves across lane^32, publish both
    // query sets (cols l31 / l31+32 of pmin row).
    float mA = fminf(fminf(fminf(mnA[0], mnA[1]),   fminf(mnA[2], mnA[3])),
                     fminf(fminf(mnA[4], mnA[5]),   fminf(mnA[6], mnA[7])));
    mA = fminf(mA, fminf(fminf(fminf(mnA[8], mnA[9]),   fminf(mnA[10], mnA[11])),
                         fminf(fminf(mnA[12], mnA[13]), fminf(mnA[14], mnA[15]))));
    float mB = fminf(fminf(fminf(mnB[0], mnB[1]),   fminf(mnB[2], mnB[3])),
                     fminf(fminf(mnB[4], mnB[5]),   fminf(mnB[6], mnB[7])));
    mB = fminf(mB, fminf(fminf(fminf(mnB[8], mnB[9]),   fminf(mnB[10], mnB[11])),
                         fminf(fminf(mnB[12], mnB[13]), fminf(mnB[14], mnB[15]))));
    mA = fminf(mA, __shfl_xor(mA, 32));
    mB = fminf(mB, __shfl_xor(mB, 32));
    if (lo) {
        pmin[wave][l31]      = mA;
        pmin[wave][l31 + 32] = mB;
    }
    __syncthreads();

    // Waves 0-3: all 64 lanes finish one query each (query = ng*256 + wave*64 + lane):
    // merge candidate halves (wave w vs w+4), add |p|^2, sqrt, full-wave sum.
    if (wave < 4) {
        float mm = fminf(pmin[wave][lane], pmin[wave + 4][lane]);
        Pack16 pr;
        pr.f4 = qpack[(size_t)b * NPTS + ng * QPB + wave * 64 + lane];
        float psq = (float)pr.h[3] + (float)pr.h[4];
        float dist = sqrtf(fmaxf(mm + psq, 0.0f));
#pragma unroll
        for (int off = 1; off <= 32; off <<= 1)
            dist += __shfl_xor(dist, off);
        if (lane == 0) wsum[wave] = dist;
    }
    __syncthreads();

    if (tid == 0)
        blocksum[blockIdx.x] = (wsum[0] + wsum[1]) + (wsum[2] + wsum[3]);
}

__global__ __launch_bounds__(256) void chamfer_finish(
    const float4* __restrict__ bs, float* __restrict__ out)
{
    __shared__ float ws[4];
    int tid = threadIdx.x;
    float s = 0.0f;
    if (tid < 128) {                      // 512 block sums = 128 x float4
        float4 v = bs[tid];
        s = (v.x + v.y) + (v.z + v.w);
    }
#pragma unroll
    for (int off = 1; off <= 32; off <<= 1)
        s += __shfl_xor(s, off);
    int lane = tid & 63, wave = tid >> 6;
    if (lane == 0) ws[wave] = s;
    __syncthreads();
    if (tid == 0) out[0] = (ws[0] + ws[1] + ws[2] + ws[3]) * (1.0f / (float)NITEMS);
}

extern "C" void kernel_launch(void* const* d_in, const int* in_sizes, int n_in,
                              void* d_out, int out_size, void* d_ws, size_t ws_size,
                              hipStream_t stream) {
    const float* pred   = (const float*)d_in[0];
    const float* target = (const float*)d_in[1];
    float* out = (float*)d_out;

    float4* packP = (float4*)d_ws;                              // 1 MB
    float4* packT = packP + (size_t)BATCH * NPTS;               // 1 MB
    float*  blocksum = (float*)(packT + (size_t)BATCH * NPTS);  // 2 KB

    chamfer_prep<<<NITEMS / 256, 256, 0, stream>>>(pred, target, packP, packT);
    chamfer_main<<<MAIN_BLOCKS, THREADS, 0, stream>>>(packP, packT, blocksum);
    chamfer_finish<<<1, 256, 0, stream>>>((const float4*)blocksum, out);
}